// Round 5
// baseline (1199.505 us; speedup 1.0000x reference)
//
#include <hip/hip_runtime.h>
#include <hip/hip_bf16.h>

#define N_NODES 3000
#define T_STEPS 64
#define POP     16
#define DEMO    32
#define ECO     16
#define R       128
#define SLOPE   0.01f

#define ROWS_PB 6
#define NBLK    500      // 500 x 6 rows = 3000 exact; 2 blocks/CU

// ---- workspace layout (floats) ----
#define WS_S1P 0
#define WS_S1D 3000
#define WS_S1E 6000
#define WS_S2P 9000
#define WS_S2D 12000
#define WS_S2E 15000
#define WS_GV  18000
#define WS_ATT 18432      // 3000
#define WS_XW  21504      // N*T*5 = 960000
#define WS_PACK_F 981504  // packed MFMA fragments (as ushort)
// pack region: per col-group w (0..7), 44 contiguous fragments of 1024 B:
//   f = kc*8 + hl*4 + g   (kc 0..3)        Whh  B-frag, hl: 0=hi 1=lo
//   f = 32 + g                             Wih+bias frag (k-slots 0..4 = Wih
//                                          hi, 6 = b_lo, 7 = b_hi)
//   f = 36 + kc*2 + hl                     lin_w B-frag (ct = w)
// ushort offset = (w*44 + f)*512 + lane*8 + i

// ---- output layout (floats) ----
#define OUT_Y    0
#define OUT_DIST 192000
#define OUT_TW   9192000
#define OUT_HT   10152000
#define OUT_CT   10536000

typedef __bf16 bf16x8 __attribute__((ext_vector_type(8)));
typedef float  f32x4  __attribute__((ext_vector_type(4)));

__device__ __forceinline__ float sigf(float x) {
  return __builtin_amdgcn_rcpf(1.0f + __expf(-x));
}
__device__ __forceinline__ float leakyf(float x) { return x >= 0.0f ? x : SLOPE * x; }
__device__ __forceinline__ float tanhfast(float x) {
  return fmaf(-2.0f, __builtin_amdgcn_rcpf(__expf(2.0f * x) + 1.0f), 1.0f);
}
__device__ __forceinline__ unsigned short bfbits(float v) {
  __bf16 b = (__bf16)v;
  return __builtin_bit_cast(unsigned short, b);
}
template <int CTRL>
__device__ __forceinline__ float dppsum(float v) {
  int p = __builtin_amdgcn_update_dpp(0, __builtin_bit_cast(int, v), CTRL, 0xF, 0xF, true);
  return v + __builtin_bit_cast(float, p);
}
#define PIN1(x) asm volatile("" : "+v"(x))

// ---------------------------------------------------------------------------
// Kernel 0: pack weights into per-wave contiguous streamed-fragment layout.
// B-frag 16x16x32: lane l elem i -> B[k=(l>>4)*8+i (+kc*32)][n = tile*16 + (l&15)]
// ---------------------------------------------------------------------------
__global__ __launch_bounds__(256) void pack_kernel(
    const float* __restrict__ Whh, const float* __restrict__ lin_w,
    const float* __restrict__ Wih, const float* __restrict__ b_lstm,
    unsigned short* __restrict__ wsu)
{
  int idx = blockIdx.x * 256 + threadIdx.x;   // 704*256 = 180224 exact
  int i    = idx & 7;
  int t1   = idx >> 3;
  int lane = t1 & 63;
  int t2   = t1 >> 6;          // < 352
  int f    = t2 % 44;
  int w    = t2 / 44;

  int ks = ((lane >> 4) << 3) + i;    // k-slot within a 32-wide K chunk
  int nc = lane & 15;
  unsigned short o = 0;

  if (f < 32) {
    int kc = f >> 3, hl = (f >> 2) & 1, g = f & 3;
    int k = kc * 32 + ks;
    int n = g * 128 + w * 16 + nc;
    float v = Whh[k * 512 + n];
    o = hl ? bfbits(v - (float)(__bf16)v) : bfbits(v);
  } else if (f < 36) {
    int g = f - 32;
    int n = g * 128 + w * 16 + nc;
    if (ks < 5)      o = bfbits(Wih[ks * 512 + n]);
    else if (ks == 6) { float b = b_lstm[n]; o = bfbits(b - (float)(__bf16)b); }
    else if (ks == 7) o = bfbits(b_lstm[n]);
  } else {
    int q = f - 36;
    int kc = q >> 1, hl = q & 1;
    int k = kc * 32 + ks;
    int n = w * 16 + nc;
    float v = lin_w[k * R + n];
    o = hl ? bfbits(v - (float)(__bf16)v) : bfbits(v);
  }
  wsu[idx] = o;
}

// ---------------------------------------------------------------------------
// Kernel 1: per-node pair-score vectors (unchanged)
// ---------------------------------------------------------------------------
__global__ __launch_bounds__(256) void scores_kernel(
    const float* __restrict__ pop,  const float* __restrict__ demo,
    const float* __restrict__ eco,
    const float* __restrict__ W_pop,  const float* __restrict__ a_pop,
    const float* __restrict__ W_demo, const float* __restrict__ a_demo,
    const float* __restrict__ W_eco,  const float* __restrict__ a_eco,
    const float* __restrict__ W_geo,  const float* __restrict__ a_geo,
    float* __restrict__ ws)
{
  int i = blockIdx.x * blockDim.x + threadIdx.x;
  if (i == 0) {
    float a0 = a_geo[0], a1 = a_geo[1];
    ws[WS_GV + 0] = W_geo[0] * a0 + W_geo[1] * a1;
    ws[WS_GV + 1] = W_geo[2] * a0 + W_geo[3] * a1;
  }
  if (i >= N_NODES) return;
  {
    float x[POP];
#pragma unroll
    for (int k = 0; k < POP; k++) x[k] = pop[i * POP + k];
    float s1 = 0.f, s2 = 0.f;
#pragma unroll
    for (int r = 0; r < POP; r++) {
      float h = 0.f;
#pragma unroll
      for (int k = 0; k < POP; k++) h = fmaf(x[k], W_pop[k * POP + r], h);
      s1 = fmaf(h, a_pop[r], s1);
      s2 = fmaf(h, a_pop[POP + r], s2);
    }
    ws[WS_S1P + i] = s1; ws[WS_S2P + i] = s2;
  }
  {
    float x[DEMO];
#pragma unroll
    for (int k = 0; k < DEMO; k++) x[k] = demo[i * DEMO + k];
    float s1 = 0.f, s2 = 0.f;
#pragma unroll 4
    for (int r = 0; r < DEMO; r++) {
      float h = 0.f;
#pragma unroll
      for (int k = 0; k < DEMO; k++) h = fmaf(x[k], W_demo[k * DEMO + r], h);
      s1 = fmaf(h, a_demo[r], s1);
      s2 = fmaf(h, a_demo[DEMO + r], s2);
    }
    ws[WS_S1D + i] = s1; ws[WS_S2D + i] = s2;
  }
  {
    float x[ECO];
#pragma unroll
    for (int k = 0; k < ECO; k++) x[k] = eco[i * ECO + k];
    float s1 = 0.f, s2 = 0.f;
#pragma unroll
    for (int r = 0; r < ECO; r++) {
      float h = 0.f;
#pragma unroll
      for (int k = 0; k < ECO; k++) h = fmaf(x[k], W_eco[k * ECO + r], h);
      s1 = fmaf(h, a_eco[r], s1);
      s2 = fmaf(h, a_eco[ECO + r], s2);
    }
    ws[WS_S1E + i] = s1; ws[WS_S2E + i] = s2;
  }
}

// ---------------------------------------------------------------------------
// Kernel 2: gate MLPs (unchanged)
// ---------------------------------------------------------------------------
__global__ __launch_bounds__(256) void weights_kernel(
    const float* __restrict__ dyn,
    const float* __restrict__ cw_w1, const float* __restrict__ cw_b1,
    const float* __restrict__ cw_w2, const float* __restrict__ cw_b2,
    const float* __restrict__ hw_w1, const float* __restrict__ hw_b1,
    const float* __restrict__ hw_w2, const float* __restrict__ hw_b2,
    float* __restrict__ out, float* __restrict__ ws)
{
  __shared__ float s_cw1[R], s_cb1[R], s_cw2[R], s_hb1[R];
  __shared__ float s_hw1[4 * R], s_hw2[R * 4];
  int tid = threadIdx.x;
  if (tid < R) {
    s_cw1[tid] = cw_w1[tid]; s_cb1[tid] = cw_b1[tid];
    s_cw2[tid] = cw_w2[tid]; s_hb1[tid] = hw_b1[tid];
  }
  for (int i = tid; i < 4 * R; i += 256) { s_hw1[i] = hw_w1[i]; s_hw2[i] = hw_w2[i]; }
  __syncthreads();

  int idx = blockIdx.x * 256 + tid;
  float x0 = dyn[idx * 5 + 0], x1 = dyn[idx * 5 + 1], x2 = dyn[idx * 5 + 2];
  float x3 = dyn[idx * 5 + 3], x4 = dyn[idx * 5 + 4];

  float acc = 0.f, o0 = 0.f, o1 = 0.f, o2 = 0.f, o3 = 0.f;
#pragma unroll 8
  for (int r = 0; r < R; r++) {
    float u = leakyf(fmaf(x0, s_cw1[r], s_cb1[r]));
    acc = fmaf(u, s_cw2[r], acc);
    float v = s_hb1[r];
    v = fmaf(x1, s_hw1[r], v);
    v = fmaf(x2, s_hw1[R + r], v);
    v = fmaf(x3, s_hw1[2 * R + r], v);
    v = fmaf(x4, s_hw1[3 * R + r], v);
    v = leakyf(v);
    o0 = fmaf(v, s_hw2[r * 4 + 0], o0);
    o1 = fmaf(v, s_hw2[r * 4 + 1], o1);
    o2 = fmaf(v, s_hw2[r * 4 + 2], o2);
    o3 = fmaf(v, s_hw2[r * 4 + 3], o3);
  }
  float tw0 = sigf(acc + cw_b2[0]);
  float tw1 = sigf(o0 + hw_b2[0]);
  float tw2 = sigf(o1 + hw_b2[1]);
  float tw3 = sigf(o2 + hw_b2[2]);
  float tw4 = sigf(o3 + hw_b2[3]);

  out[OUT_TW + idx * 5 + 0] = tw0;
  out[OUT_TW + idx * 5 + 1] = tw1;
  out[OUT_TW + idx * 5 + 2] = tw2;
  out[OUT_TW + idx * 5 + 3] = tw3;
  out[OUT_TW + idx * 5 + 4] = tw4;

  ws[WS_XW + idx * 5 + 0] = tw0 * x0;
  ws[WS_XW + idx * 5 + 1] = tw1 * x1;
  ws[WS_XW + idx * 5 + 2] = tw2 * x2;
  ws[WS_XW + idx * 5 + 3] = tw3 * x3;
  ws[WS_XW + idx * 5 + 4] = tw4 * x4;
}

// ---------------------------------------------------------------------------
// Kernel 3: dist rows + att_scale (unchanged)
// ---------------------------------------------------------------------------
__global__ __launch_bounds__(256) void dist_kernel(
    const float* __restrict__ geo, float* __restrict__ out, float* __restrict__ ws)
{
  int i = blockIdx.x;
  int tid = threadIdx.x;
  __shared__ float sm[20];

  float s1p = ws[WS_S1P + i], s1d = ws[WS_S1D + i], s1e = ws[WS_S1E + i];
  float gv0 = ws[WS_GV + 0], gv1 = ws[WS_GV + 1];

  float vals[12];
  float vmax = -3.0e38f;
#pragma unroll
  for (int u = 0; u < 12; u++) {
    int j = tid + u * 256;
    float v = -3.0e38f;
    if (j < N_NODES) {
      float2 g = *(const float2*)&geo[((size_t)i * N_NODES + j) * 2];
      v = sigf(s1p + ws[WS_S2P + j]) + sigf(s1d + ws[WS_S2D + j]) +
          sigf(s1e + ws[WS_S2E + j]) + sigf(fmaf(g.x, gv0, g.y * gv1));
    }
    vals[u] = v;
    vmax = fmaxf(vmax, v);
  }
  int wid = tid >> 6, lane = tid & 63;
  for (int off = 32; off; off >>= 1) vmax = fmaxf(vmax, __shfl_down(vmax, off, 64));
  if (lane == 0) sm[wid] = vmax;
  __syncthreads();
  if (tid == 0) sm[8] = fmaxf(fmaxf(sm[0], sm[1]), fmaxf(sm[2], sm[3]));
  __syncthreads();
  vmax = sm[8];

  float lsum = 0.f;
#pragma unroll
  for (int u = 0; u < 12; u++) {
    int j = tid + u * 256;
    float e = (j < N_NODES) ? __expf(vals[u] - vmax) : 0.f;
    vals[u] = e;
    lsum += e;
  }
  for (int off = 32; off; off >>= 1) lsum += __shfl_down(lsum, off, 64);
  if (lane == 0) sm[4 + wid] = lsum;
  __syncthreads();
  if (tid == 0) sm[9] = sm[4] + sm[5] + sm[6] + sm[7];
  __syncthreads();
  float inv = __builtin_amdgcn_rcpf(sm[9]);

  float rs = 0.f;
#pragma unroll
  for (int u = 0; u < 12; u++) {
    int j = tid + u * 256;
    if (j < N_NODES) {
      float wv = vals[u] * inv;
      out[OUT_DIST + (size_t)i * N_NODES + j] = wv;
      rs += wv;
    }
  }
  for (int off = 32; off; off >>= 1) rs += __shfl_down(rs, off, 64);
  if (lane == 0) sm[10 + wid] = rs;
  __syncthreads();
  if (tid == 0) ws[WS_ATT + i] = 1.0f + (sm[10] + sm[11] + sm[12] + sm[13]);
}

// ---------------------------------------------------------------------------
// Kernel 4: persistent MFMA LSTM, L2-STREAMED weight fragments.
// 500 blocks x 512 thr x 6 rows. VGPR capped at 128 -> 2 blocks/CU,
// 4 waves/SIMD with DECOUPLED barriers (co-resident blocks hide each
// other's stalls). Fragments re-loaded from L2 each step (352 KB region,
// L2-resident; ~700 B/wave/step). Same h layout / DPP head pipeline /
// 1 barrier per step as round 4.
// ---------------------------------------------------------------------------
#define HB        6144    // per buffer: h-hi [0,4096) + xw-hi [4096,5120) + xw-lo [5120,6144)
#define XWH       4096
#define XWL       5120
#define PART_OFF  12288   // 2 parities x 16 rows x 8 waves f32 = 1024 B
#define LDS_BYTES 13312
#define WGRP_B    45056   // bytes per col-group (44 frags x 1024)

__global__ __launch_bounds__(512, 4) void lstm_kernel(
    const unsigned short* __restrict__ wsu,
    const float* __restrict__ ws,
    const float* __restrict__ lin_b, const float* __restrict__ lin2_w,
    const float* __restrict__ lin2_b,
    float* __restrict__ out)
{
  __shared__ __align__(16) char smraw[LDS_BYTES];
  float* PARTf = (float*)(smraw + PART_OFF);
  int tid = threadIdx.x;
  int w = tid >> 6, lane = tid & 63;
  int lg = lane >> 4, lc = lane & 15;
  int row0 = blockIdx.x * ROWS_PB;

  // per-wave fragment base (all 44 frags contiguous from here, stride 1024 B)
  const char* wb = (const char*)wsu + w * WGRP_B + lane * 16;

  int hcol = w * 16 + lc;
  float lbv = lin_b[hcol], l2v = lin2_w[hcol], l2b = lin2_b[0];
  float sc[4];
#pragma unroll
  for (int j = 0; j < 4; j++) {
    int rg = row0 + lg * 4 + j; if (rg > 2999) rg = 2999;
    sc[j] = ws[WS_ATT + rg];
    PIN1(sc[j]);
  }
  PIN1(lbv); PIN1(l2v); PIN1(l2b);

  // ---- init LDS ----
  for (int p = tid; p < LDS_BYTES / 4; p += 512) ((float*)smraw)[p] = 0.f;
  __syncthreads();
  if (tid < 32) {   // 1.0 at bias A-slots (k=6,7 of kc4) in BOTH buffers' xw-hi
    int b = tid >> 4, r = tid & 15;
    *(unsigned short*)(smraw + b * HB + XWH + r * 16 + 12) = 0x3F80;
    *(unsigned short*)(smraw + b * HB + XWH + r * 16 + 14) = 0x3F80;
  }
  int pr = tid / 5, pd = tid - pr * 5;
  int prow = row0 + pr; if (prow > 2999) prow = 2999;
  const float* xw_row = ws + WS_XW + (size_t)prow * 320;
  if (tid < 80) {   // xw(0) -> buf0
    float v = xw_row[pd];
    float vh = (float)(__bf16)v;
    *(unsigned short*)(smraw + XWH + pr * 16 + pd * 2) = bfbits(v);
    *(unsigned short*)(smraw + XWL + pr * 16 + pd * 2) = bfbits(v - vh);
  }
  __syncthreads();

  // per-lane h-write base (fragment-linear layout, hi only)
  int hi3 = (2 * w + (lc >> 3)) & 3;
  int hwbase = (w >> 1) * 1024 + hi3 * 256 + (lc & 7) * 2;

  bf16x8 ah[4];                 // h_{t-1} hi A-frags, carried in registers
  f32x4 zf4 = {0.f, 0.f, 0.f, 0.f};
#pragma unroll
  for (int kc = 0; kc < 4; kc++) ah[kc] = __builtin_bit_cast(bf16x8, zf4);
  float cst[4] = {0.f, 0.f, 0.f, 0.f};
  float val[4] = {0.f, 0.f, 0.f, 0.f};

#pragma unroll 1
  for (int t = 0; t < T_STEPS; t++) {
    char* bufcur = smraw + (t & 1) * HB;
    char* bufnxt = smraw + ((t & 1) ^ 1) * HB;

    // prefetch xw(t+1) from L2 (hidden under Phase A)
    float xnext = 0.f;
    if (tid < 80) {
      int tn = t + 1 < T_STEPS ? t + 1 : T_STEPS - 1;
      xnext = xw_row[tn * 5 + pd];
    }

    // ---- head reduce of step t-1 (DPP, fills Phase A's shadow) ------------
    if (t > 0) {
#pragma unroll
      for (int j = 0; j < 4; j++) {
        float v = val[j];
        v = dppsum<0xB1>(v); v = dppsum<0x4E>(v);
        v = dppsum<0x141>(v); v = dppsum<0x140>(v);
        if (lc == 0) PARTf[((t - 1) & 1) * 128 + (lg * 4 + j) * 8 + w] = v;
      }
    }

    // ---- Phase A: z = [h|xw|1] @ [Whh;Wih;b]  (bf16x2, B streamed) --------
    bf16x8 a4h = *(const bf16x8*)(bufcur + XWH + lane * 16);
    bf16x8 a4l = *(const bf16x8*)(bufcur + XWL + lane * 16);
    f32x4 acc[4];
#pragma unroll
    for (int g = 0; g < 4; g++) acc[g] = zf4;
#pragma unroll
    for (int kc = 0; kc < 4; kc++) {
      bf16x8 b0 = *(const bf16x8*)(wb + (kc * 8 + 0) * 1024);
      bf16x8 b1 = *(const bf16x8*)(wb + (kc * 8 + 1) * 1024);
      bf16x8 b2 = *(const bf16x8*)(wb + (kc * 8 + 2) * 1024);
      bf16x8 b3 = *(const bf16x8*)(wb + (kc * 8 + 3) * 1024);
      bf16x8 b4 = *(const bf16x8*)(wb + (kc * 8 + 4) * 1024);
      bf16x8 b5 = *(const bf16x8*)(wb + (kc * 8 + 5) * 1024);
      bf16x8 b6 = *(const bf16x8*)(wb + (kc * 8 + 6) * 1024);
      bf16x8 b7 = *(const bf16x8*)(wb + (kc * 8 + 7) * 1024);
      acc[0] = __builtin_amdgcn_mfma_f32_16x16x32_bf16(ah[kc], b0, acc[0], 0, 0, 0);
      acc[1] = __builtin_amdgcn_mfma_f32_16x16x32_bf16(ah[kc], b1, acc[1], 0, 0, 0);
      acc[2] = __builtin_amdgcn_mfma_f32_16x16x32_bf16(ah[kc], b2, acc[2], 0, 0, 0);
      acc[3] = __builtin_amdgcn_mfma_f32_16x16x32_bf16(ah[kc], b3, acc[3], 0, 0, 0);
      acc[0] = __builtin_amdgcn_mfma_f32_16x16x32_bf16(ah[kc], b4, acc[0], 0, 0, 0);
      acc[1] = __builtin_amdgcn_mfma_f32_16x16x32_bf16(ah[kc], b5, acc[1], 0, 0, 0);
      acc[2] = __builtin_amdgcn_mfma_f32_16x16x32_bf16(ah[kc], b6, acc[2], 0, 0, 0);
      acc[3] = __builtin_amdgcn_mfma_f32_16x16x32_bf16(ah[kc], b7, acc[3], 0, 0, 0);
    }
    {
      bf16x8 c0 = *(const bf16x8*)(wb + 32 * 1024);
      bf16x8 c1 = *(const bf16x8*)(wb + 33 * 1024);
      bf16x8 c2 = *(const bf16x8*)(wb + 34 * 1024);
      bf16x8 c3 = *(const bf16x8*)(wb + 35 * 1024);
      acc[0] = __builtin_amdgcn_mfma_f32_16x16x32_bf16(a4h, c0, acc[0], 0, 0, 0);
      acc[1] = __builtin_amdgcn_mfma_f32_16x16x32_bf16(a4h, c1, acc[1], 0, 0, 0);
      acc[2] = __builtin_amdgcn_mfma_f32_16x16x32_bf16(a4h, c2, acc[2], 0, 0, 0);
      acc[3] = __builtin_amdgcn_mfma_f32_16x16x32_bf16(a4h, c3, acc[3], 0, 0, 0);
      acc[0] = __builtin_amdgcn_mfma_f32_16x16x32_bf16(a4l, c0, acc[0], 0, 0, 0);
      acc[1] = __builtin_amdgcn_mfma_f32_16x16x32_bf16(a4l, c1, acc[1], 0, 0, 0);
      acc[2] = __builtin_amdgcn_mfma_f32_16x16x32_bf16(a4l, c2, acc[2], 0, 0, 0);
      acc[3] = __builtin_amdgcn_mfma_f32_16x16x32_bf16(a4l, c3, acc[3], 0, 0, 0);
    }

    // ---- gates (z in registers), write h-hi -> bufcur ---------------------
    float hval[4];
#pragma unroll
    for (int j = 0; j < 4; j++) {
      float ig = sigf(acc[0][j]), fg = sigf(acc[1][j]);
      float gg = tanhfast(acc[2][j]), og = sigf(acc[3][j]);
      float cn = fmaf(fg, cst[j], ig * gg);
      float hn = og * tanhfast(cn);
      cst[j] = cn; hval[j] = hn;
      *(unsigned short*)(bufcur + hwbase + (lg * 4 + j) * 16) = bfbits(hn);
    }

    // issue lin_w fragment loads now; they stay in flight across the barrier
    bf16x8 p0 = *(const bf16x8*)(wb + 36 * 1024);
    bf16x8 p1 = *(const bf16x8*)(wb + 37 * 1024);
    bf16x8 p2 = *(const bf16x8*)(wb + 38 * 1024);
    bf16x8 p3 = *(const bf16x8*)(wb + 39 * 1024);
    bf16x8 p4 = *(const bf16x8*)(wb + 40 * 1024);
    bf16x8 p5 = *(const bf16x8*)(wb + 41 * 1024);
    bf16x8 p6 = *(const bf16x8*)(wb + 42 * 1024);
    bf16x8 p7 = *(const bf16x8*)(wb + 43 * 1024);

    if (tid < 80) {   // xw(t+1) -> other buffer (no reader until next barrier)
      float vh = (float)(__bf16)xnext;
      *(unsigned short*)(bufnxt + XWH + pr * 16 + pd * 2) = bfbits(xnext);
      *(unsigned short*)(bufnxt + XWL + pr * 16 + pd * 2) = bfbits(xnext - vh);
    }
    if (t == T_STEPS - 1) {
#pragma unroll
      for (int j = 0; j < 4; j++) {
        int r = lg * 4 + j;
        if (r < ROWS_PB) {
          out[OUT_HT + (size_t)(row0 + r) * R + hcol] = hval[j];
          out[OUT_CT + (size_t)(row0 + r) * R + hcol] = cst[j];
        }
      }
    }
    __syncthreads();   // the ONLY barrier per step

    // ---- y(t-1) final sum (overlaps Phase C) ------------------------------
    if (t > 0 && tid < ROWS_PB) {
      const float* pp = PARTf + ((t - 1) & 1) * 128 + tid * 8;
      float s = l2b;
#pragma unroll
      for (int p = 0; p < 8; p++) s += pp[p];
      out[OUT_Y + (size_t)(row0 + tid) * T_STEPS + (t - 1)] = s;
    }

    // ---- Phase C: G = h_t @ lin_w; A-frags carried into next Phase A ------
#pragma unroll
    for (int kc = 0; kc < 4; kc++)
      ah[kc] = *(const bf16x8*)(bufcur + kc * 1024 + lane * 16);
    f32x4 ga = zf4, gb = zf4;
    ga = __builtin_amdgcn_mfma_f32_16x16x32_bf16(ah[0], p0, ga, 0, 0, 0);
    ga = __builtin_amdgcn_mfma_f32_16x16x32_bf16(ah[0], p1, ga, 0, 0, 0);
    ga = __builtin_amdgcn_mfma_f32_16x16x32_bf16(ah[1], p2, ga, 0, 0, 0);
    ga = __builtin_amdgcn_mfma_f32_16x16x32_bf16(ah[1], p3, ga, 0, 0, 0);
    gb = __builtin_amdgcn_mfma_f32_16x16x32_bf16(ah[2], p4, gb, 0, 0, 0);
    gb = __builtin_amdgcn_mfma_f32_16x16x32_bf16(ah[2], p5, gb, 0, 0, 0);
    gb = __builtin_amdgcn_mfma_f32_16x16x32_bf16(ah[3], p6, gb, 0, 0, 0);
    gb = __builtin_amdgcn_mfma_f32_16x16x32_bf16(ah[3], p7, gb, 0, 0, 0);
#pragma unroll
    for (int j = 0; j < 4; j++)
      val[j] = leakyf(fmaf(sc[j], ga[j] + gb[j], lbv)) * l2v;
  }

  // ---- tail: y(63) ----
#pragma unroll
  for (int j = 0; j < 4; j++) {
    float v = val[j];
    v = dppsum<0xB1>(v); v = dppsum<0x4E>(v);
    v = dppsum<0x141>(v); v = dppsum<0x140>(v);
    if (lc == 0) PARTf[128 + (lg * 4 + j) * 8 + w] = v;   // parity 63&1 = 1
  }
  __syncthreads();
  if (tid < ROWS_PB) {
    const float* pp = PARTf + 128 + tid * 8;
    float s = l2b;
#pragma unroll
    for (int p = 0; p < 8; p++) s += pp[p];
    out[OUT_Y + (size_t)(row0 + tid) * T_STEPS + 63] = s;
  }
}

// ---------------------------------------------------------------------------
extern "C" void kernel_launch(void* const* d_in, const int* in_sizes, int n_in,
                              void* d_out, int out_size, void* d_ws, size_t ws_size,
                              hipStream_t stream) {
  const float* dynamic = (const float*)d_in[0];
  const float* pop     = (const float*)d_in[1];
  const float* demo    = (const float*)d_in[2];
  const float* eco     = (const float*)d_in[3];
  const float* geo     = (const float*)d_in[4];
  const float* W_pop   = (const float*)d_in[5];
  const float* a_pop   = (const float*)d_in[6];
  const float* W_demo  = (const float*)d_in[7];
  const float* a_demo  = (const float*)d_in[8];
  const float* W_eco   = (const float*)d_in[9];
  const float* a_eco   = (const float*)d_in[10];
  const float* W_geo   = (const float*)d_in[11];
  const float* a_geo   = (const float*)d_in[12];
  const float* cw_w1   = (const float*)d_in[13];
  const float* cw_b1   = (const float*)d_in[14];
  const float* cw_w2   = (const float*)d_in[15];
  const float* cw_b2   = (const float*)d_in[16];
  const float* hw_w1   = (const float*)d_in[17];
  const float* hw_b1   = (const float*)d_in[18];
  const float* hw_w2   = (const float*)d_in[19];
  const float* hw_b2   = (const float*)d_in[20];
  const float* Wih     = (const float*)d_in[21];
  const float* Whh     = (const float*)d_in[22];
  const float* b_lstm  = (const float*)d_in[23];
  const float* lin_w   = (const float*)d_in[24];
  const float* lin_b   = (const float*)d_in[25];
  const float* lin2_w  = (const float*)d_in[26];
  const float* lin2_b  = (const float*)d_in[27];

  float* out = (float*)d_out;
  float* ws  = (float*)d_ws;
  unsigned short* wsu = (unsigned short*)(ws + WS_PACK_F);

  pack_kernel<<<704, 256, 0, stream>>>(Whh, lin_w, Wih, b_lstm, wsu);
  scores_kernel<<<12, 256, 0, stream>>>(pop, demo, eco, W_pop, a_pop,
                                        W_demo, a_demo, W_eco, a_eco,
                                        W_geo, a_geo, ws);
  weights_kernel<<<750, 256, 0, stream>>>(dynamic, cw_w1, cw_b1, cw_w2, cw_b2,
                                          hw_w1, hw_b1, hw_w2, hw_b2, out, ws);
  dist_kernel<<<N_NODES, 256, 0, stream>>>(geo, out, ws);
  lstm_kernel<<<NBLK, 512, 0, stream>>>(wsu, ws, lin_b, lin2_w, lin2_b, out);
}